// Round 9
// baseline (124.535 us; speedup 1.0000x reference)
//
#include <hip/hip_runtime.h>
#include <math.h>

#define B_TOK 8192
#define NB 4
#define CH 2048
#define TPB 512            // 8 waves/block
#define NBLK 1024          // 8 tokens per block
#define TOK_PER_BLK 8
#define SINK_ITERS 20
#define EPS 1e-5f

typedef float f32x4 __attribute__((ext_vector_type(4)));

__device__ __forceinline__ float bcast_first(float v) {
    return __uint_as_float(__builtin_amdgcn_readfirstlane(__float_as_uint(v)));
}
__device__ __forceinline__ float read_lane(float v, int l) {
    return __uint_as_float(__builtin_amdgcn_readlane(__float_as_uint(v), l));
}

// R8 structure with __launch_bounds__(512, 8): force VGPR<=64 so 4 blocks/CU
// (32 waves/CU) stay resident. Single-lever A/B vs R8 (102.0us).
__global__ __launch_bounds__(TPB, 8) void mhc_fused(
    const float* __restrict__ x,
    const float* __restrict__ w,
    const float* __restrict__ H_pre,
    const float* __restrict__ H_post,
    const float* __restrict__ H_res,
    float* __restrict__ y)
{
    const int t = threadIdx.x;
    const int wave = t >> 6;
    const int lane = t & 63;
    const int b0 = blockIdx.x * TOK_PER_BLK;

    __shared__ float red[2][32];   // [phase][wave*4 + branch]

    // ---- Issue first loads BEFORE sinkhorn math (latency overlap) ----
    f32x4 xA0, xA1, xA2, xA3, xB0, xB1, xB2, xB3;
    auto xload = [&](int b, f32x4& d0, f32x4& d1, f32x4& d2, f32x4& d3) {
        const f32x4* p = (const f32x4*)x + (size_t)b * (NB * CH / 4) + t;
        d0 = __builtin_nontemporal_load(p);
        d1 = __builtin_nontemporal_load(p + (CH / 4));
        d2 = __builtin_nontemporal_load(p + 2 * (CH / 4));
        d3 = __builtin_nontemporal_load(p + 3 * (CH / 4));
    };
    xload(b0 + 0, xA0, xA1, xA2, xA3);
    xload(b0 + 1, xB0, xB1, xB2, xB3);
    const f32x4 wv = ((const f32x4*)w)[t];

    // ---- Lane-parallel Sinkhorn (runs while the loads above are in flight) --
    const int e = lane & 15;
    float v = expf(H_res[e]);
    #pragma unroll 1
    for (int it = 0; it < SINK_ITERS; ++it) {
        float s = v + __shfl_xor(v, 1);
        s += __shfl_xor(s, 2);
        v *= __builtin_amdgcn_rcpf(s + EPS);
        s = v + __shfl_xor(v, 4);
        s += __shfl_xor(s, 8);
        v *= __builtin_amdgcn_rcpf(s + EPS);
    }
    const float H00 = read_lane(v, 0),  H01 = read_lane(v, 1),
                H02 = read_lane(v, 2),  H03 = read_lane(v, 3);
    const float H10 = read_lane(v, 4),  H11 = read_lane(v, 5),
                H12 = read_lane(v, 6),  H13 = read_lane(v, 7);
    const float H20 = read_lane(v, 8),  H21 = read_lane(v, 9),
                H22 = read_lane(v, 10), H23 = read_lane(v, 11);
    const float H30 = read_lane(v, 12), H31 = read_lane(v, 13),
                H32 = read_lane(v, 14), H33 = read_lane(v, 15);

    const float pre0 = bcast_first(1.0f / (1.0f + expf(-H_pre[0])));
    const float pre1 = bcast_first(1.0f / (1.0f + expf(-H_pre[1])));
    const float pre2 = bcast_first(1.0f / (1.0f + expf(-H_pre[2])));
    const float pre3 = bcast_first(1.0f / (1.0f + expf(-H_pre[3])));
    const float ps0  = bcast_first(1.0f / (1.0f + expf(-H_post[0])));
    const float ps1  = bcast_first(1.0f / (1.0f + expf(-H_post[1])));
    const float ps2  = bcast_first(1.0f / (1.0f + expf(-H_post[2])));
    const float ps3  = bcast_first(1.0f / (1.0f + expf(-H_post[3])));

    auto process = [&](int b, f32x4 x0, f32x4 x1, f32x4 x2, f32x4 x3, int ph) {
        float s0 = x0.x * x0.x + x0.y * x0.y + x0.z * x0.z + x0.w * x0.w;
        float s1 = x1.x * x1.x + x1.y * x1.y + x1.z * x1.z + x1.w * x1.w;
        float s2 = x2.x * x2.x + x2.y * x2.y + x2.z * x2.z + x2.w * x2.w;
        float s3 = x3.x * x3.x + x3.y * x3.y + x3.z * x3.z + x3.w * x3.w;

        // Fold 4 values -> 1 per lane (3 shuffles), then 4-step butterfly.
        float a01 = (lane & 1) ? s1 : s0;
        float b01 = (lane & 1) ? s0 : s1;
        a01 += __shfl_xor(b01, 1);
        float a23 = (lane & 1) ? s3 : s2;
        float b23 = (lane & 1) ? s2 : s3;
        a23 += __shfl_xor(b23, 1);
        float c = (lane & 2) ? a23 : a01;
        float d = (lane & 2) ? a01 : a23;
        c += __shfl_xor(d, 2);
        c += __shfl_xor(c, 4);
        c += __shfl_xor(c, 8);
        c += __shfl_xor(c, 16);
        c += __shfl_xor(c, 32);
        if (lane < 4) red[ph][wave * 4 + lane] = c;

        // LDS-only barrier: do NOT drain vmcnt (prefetch loads stay in flight)
        __builtin_amdgcn_sched_barrier(0);
        asm volatile("s_waitcnt lgkmcnt(0)" ::: "memory");
        __builtin_amdgcn_s_barrier();
        __builtin_amdgcn_sched_barrier(0);

        // Cross-wave combine: conflict-free read, 3 shuffles, 4 readlane.
        float vv = red[ph][lane & 31];
        vv += __shfl_xor(vv, 4);
        vv += __shfl_xor(vv, 8);
        vv += __shfl_xor(vv, 16);
        const float t0 = read_lane(vv, 0);
        const float t1 = read_lane(vv, 1);
        const float t2 = read_lane(vv, 2);
        const float t3 = read_lane(vv, 3);

        const float a0 = pre0 * rsqrtf(t0 * (1.0f / CH) + EPS);
        const float a1 = pre1 * rsqrtf(t1 * (1.0f / CH) + EPS);
        const float a2 = pre2 * rsqrtf(t2 * (1.0f / CH) + EPS);
        const float a3 = pre3 * rsqrtf(t3 * (1.0f / CH) + EPS);

        f32x4 wu;
        wu.x = wv.x * (a0 * x0.x + a1 * x1.x + a2 * x2.x + a3 * x3.x);
        wu.y = wv.y * (a0 * x0.y + a1 * x1.y + a2 * x2.y + a3 * x3.y);
        wu.z = wv.z * (a0 * x0.z + a1 * x1.z + a2 * x2.z + a3 * x3.z);
        wu.w = wv.w * (a0 * x0.w + a1 * x1.w + a2 * x2.w + a3 * x3.w);

        f32x4* yp = (f32x4*)y + (size_t)b * (NB * CH / 4) + t;
        f32x4 o;
        o.x = H00 * x0.x + H01 * x1.x + H02 * x2.x + H03 * x3.x + ps0 * wu.x;
        o.y = H00 * x0.y + H01 * x1.y + H02 * x2.y + H03 * x3.y + ps0 * wu.y;
        o.z = H00 * x0.z + H01 * x1.z + H02 * x2.z + H03 * x3.z + ps0 * wu.z;
        o.w = H00 * x0.w + H01 * x1.w + H02 * x2.w + H03 * x3.w + ps0 * wu.w;
        __builtin_nontemporal_store(o, yp);
        o.x = H10 * x0.x + H11 * x1.x + H12 * x2.x + H13 * x3.x + ps1 * wu.x;
        o.y = H10 * x0.y + H11 * x1.y + H12 * x2.y + H13 * x3.y + ps1 * wu.y;
        o.z = H10 * x0.z + H11 * x1.z + H12 * x2.z + H13 * x3.z + ps1 * wu.z;
        o.w = H10 * x0.w + H11 * x1.w + H12 * x2.w + H13 * x3.w + ps1 * wu.w;
        __builtin_nontemporal_store(o, yp + (CH / 4));
        o.x = H20 * x0.x + H21 * x1.x + H22 * x2.x + H23 * x3.x + ps2 * wu.x;
        o.y = H20 * x0.y + H21 * x1.y + H22 * x2.y + H23 * x3.y + ps2 * wu.y;
        o.z = H20 * x0.z + H21 * x1.z + H22 * x2.z + H23 * x3.z + ps2 * wu.z;
        o.w = H20 * x0.w + H21 * x1.w + H22 * x2.w + H23 * x3.w + ps2 * wu.w;
        __builtin_nontemporal_store(o, yp + 2 * (CH / 4));
        o.x = H30 * x0.x + H31 * x1.x + H32 * x2.x + H33 * x3.x + ps3 * wu.x;
        o.y = H30 * x0.y + H31 * x1.y + H32 * x2.y + H33 * x3.y + ps3 * wu.y;
        o.z = H30 * x0.z + H31 * x1.z + H32 * x2.z + H33 * x3.z + ps3 * wu.z;
        o.w = H30 * x0.w + H31 * x1.w + H32 * x2.w + H33 * x3.w + ps3 * wu.w;
        __builtin_nontemporal_store(o, yp + 3 * (CH / 4));
    };

    // Software pipeline over 8 tokens: prefetch k+1 before processing k.
    process(b0 + 0, xA0, xA1, xA2, xA3, 0);
    xload(b0 + 2, xA0, xA1, xA2, xA3);
    process(b0 + 1, xB0, xB1, xB2, xB3, 1);
    xload(b0 + 3, xB0, xB1, xB2, xB3);
    process(b0 + 2, xA0, xA1, xA2, xA3, 0);
    xload(b0 + 4, xA0, xA1, xA2, xA3);
    process(b0 + 3, xB0, xB1, xB2, xB3, 1);
    xload(b0 + 5, xB0, xB1, xB2, xB3);
    process(b0 + 4, xA0, xA1, xA2, xA3, 0);
    xload(b0 + 6, xA0, xA1, xA2, xA3);
    process(b0 + 5, xB0, xB1, xB2, xB3, 1);
    xload(b0 + 7, xB0, xB1, xB2, xB3);
    process(b0 + 6, xA0, xA1, xA2, xA3, 0);
    process(b0 + 7, xB0, xB1, xB2, xB3, 1);
}

extern "C" void kernel_launch(void* const* d_in, const int* in_sizes, int n_in,
                              void* d_out, int out_size, void* d_ws, size_t ws_size,
                              hipStream_t stream) {
    const float* x      = (const float*)d_in[0];   // [B, N, C]
    const float* wgt    = (const float*)d_in[1];   // [C]
    const float* h_pre  = (const float*)d_in[2];   // [N]
    const float* h_post = (const float*)d_in[3];   // [N]
    const float* h_res  = (const float*)d_in[4];   // [N, N]
    float* y = (float*)d_out;                      // [B, N, C]

    mhc_fused<<<NBLK, TPB, 0, stream>>>(x, wgt, h_pre, h_post, h_res, y);
}

// Round 10
// 101.293 us; speedup vs baseline: 1.2295x; 1.2295x over previous
//
#include <hip/hip_runtime.h>
#include <math.h>

#define B_TOK 8192
#define NB 4
#define CH 2048
#define TPB 512            // 8 waves/block
#define NBLK 1024          // 8 tokens per block
#define TOK_PER_BLK 8
#define SINK_ITERS 20
#define EPS 1e-5f

typedef float f32x4 __attribute__((ext_vector_type(4)));

__device__ __forceinline__ float bcast_first(float v) {
    return __uint_as_float(__builtin_amdgcn_readfirstlane(__float_as_uint(v)));
}
__device__ __forceinline__ float read_lane(float v, int l) {
    return __uint_as_float(__builtin_amdgcn_readlane(__float_as_uint(v), l));
}

// R8 structure + depth-2 prefetch with EARLY ISSUE: 3 rotating register
// buffers; next-next token's loads are issued inside process(), after the
// ss computation and BEFORE the shuffle/barrier fence, so each token has
// ~2 process-phases of load slack. Single-lever A/B vs R8 (102.0us).
__global__ __launch_bounds__(TPB) void mhc_fused(
    const float* __restrict__ x,
    const float* __restrict__ w,
    const float* __restrict__ H_pre,
    const float* __restrict__ H_post,
    const float* __restrict__ H_res,
    float* __restrict__ y)
{
    const int t = threadIdx.x;
    const int wave = t >> 6;
    const int lane = t & 63;
    const int b0 = blockIdx.x * TOK_PER_BLK;

    __shared__ float red[2][32];   // [phase][wave*4 + branch]

    // ---- Issue first loads BEFORE sinkhorn math (latency overlap) ----
    f32x4 xA0, xA1, xA2, xA3, xB0, xB1, xB2, xB3, xC0, xC1, xC2, xC3;
    auto xload = [&](int b, f32x4& d0, f32x4& d1, f32x4& d2, f32x4& d3) {
        const f32x4* p = (const f32x4*)x + (size_t)b * (NB * CH / 4) + t;
        d0 = __builtin_nontemporal_load(p);
        d1 = __builtin_nontemporal_load(p + (CH / 4));
        d2 = __builtin_nontemporal_load(p + 2 * (CH / 4));
        d3 = __builtin_nontemporal_load(p + 3 * (CH / 4));
    };
    xload(b0 + 0, xA0, xA1, xA2, xA3);
    xload(b0 + 1, xB0, xB1, xB2, xB3);
    const f32x4 wv = ((const f32x4*)w)[t];

    // ---- Lane-parallel Sinkhorn (runs while the loads above are in flight) --
    const int e = lane & 15;
    float v = expf(H_res[e]);
    #pragma unroll 1
    for (int it = 0; it < SINK_ITERS; ++it) {
        float s = v + __shfl_xor(v, 1);
        s += __shfl_xor(s, 2);
        v *= __builtin_amdgcn_rcpf(s + EPS);
        s = v + __shfl_xor(v, 4);
        s += __shfl_xor(s, 8);
        v *= __builtin_amdgcn_rcpf(s + EPS);
    }
    const float H00 = read_lane(v, 0),  H01 = read_lane(v, 1),
                H02 = read_lane(v, 2),  H03 = read_lane(v, 3);
    const float H10 = read_lane(v, 4),  H11 = read_lane(v, 5),
                H12 = read_lane(v, 6),  H13 = read_lane(v, 7);
    const float H20 = read_lane(v, 8),  H21 = read_lane(v, 9),
                H22 = read_lane(v, 10), H23 = read_lane(v, 11);
    const float H30 = read_lane(v, 12), H31 = read_lane(v, 13),
                H32 = read_lane(v, 14), H33 = read_lane(v, 15);

    const float pre0 = bcast_first(1.0f / (1.0f + expf(-H_pre[0])));
    const float pre1 = bcast_first(1.0f / (1.0f + expf(-H_pre[1])));
    const float pre2 = bcast_first(1.0f / (1.0f + expf(-H_pre[2])));
    const float pre3 = bcast_first(1.0f / (1.0f + expf(-H_pre[3])));
    const float ps0  = bcast_first(1.0f / (1.0f + expf(-H_post[0])));
    const float ps1  = bcast_first(1.0f / (1.0f + expf(-H_post[1])));
    const float ps2  = bcast_first(1.0f / (1.0f + expf(-H_post[2])));
    const float ps3  = bcast_first(1.0f / (1.0f + expf(-H_post[3])));

    // process token b (x in x0..x3); optionally prefetch token pb into p0..p3
    // BEFORE the barrier fence (early issue, ~2 phases of slack).
    auto process = [&](int b, f32x4 x0, f32x4 x1, f32x4 x2, f32x4 x3, int ph,
                       bool pf, int pb, f32x4& p0, f32x4& p1, f32x4& p2, f32x4& p3) {
        float s0 = x0.x * x0.x + x0.y * x0.y + x0.z * x0.z + x0.w * x0.w;
        float s1 = x1.x * x1.x + x1.y * x1.y + x1.z * x1.z + x1.w * x1.w;
        float s2 = x2.x * x2.x + x2.y * x2.y + x2.z * x2.z + x2.w * x2.w;
        float s3 = x3.x * x3.x + x3.y * x3.y + x3.z * x3.z + x3.w * x3.w;

        // Early prefetch issue: independent of everything below the fence.
        if (pf) {
            const f32x4* p = (const f32x4*)x + (size_t)pb * (NB * CH / 4) + t;
            p0 = __builtin_nontemporal_load(p);
            p1 = __builtin_nontemporal_load(p + (CH / 4));
            p2 = __builtin_nontemporal_load(p + 2 * (CH / 4));
            p3 = __builtin_nontemporal_load(p + 3 * (CH / 4));
        }

        // Fold 4 values -> 1 per lane (3 shuffles), then 4-step butterfly.
        float a01 = (lane & 1) ? s1 : s0;
        float b01 = (lane & 1) ? s0 : s1;
        a01 += __shfl_xor(b01, 1);
        float a23 = (lane & 1) ? s3 : s2;
        float b23 = (lane & 1) ? s2 : s3;
        a23 += __shfl_xor(b23, 1);
        float c = (lane & 2) ? a23 : a01;
        float d = (lane & 2) ? a01 : a23;
        c += __shfl_xor(d, 2);
        c += __shfl_xor(c, 4);
        c += __shfl_xor(c, 8);
        c += __shfl_xor(c, 16);
        c += __shfl_xor(c, 32);
        if (lane < 4) red[ph][wave * 4 + lane] = c;

        // LDS-only barrier: do NOT drain vmcnt (prefetch loads stay in flight)
        __builtin_amdgcn_sched_barrier(0);
        asm volatile("s_waitcnt lgkmcnt(0)" ::: "memory");
        __builtin_amdgcn_s_barrier();
        __builtin_amdgcn_sched_barrier(0);

        // Cross-wave combine: conflict-free read, 3 shuffles, 4 readlane.
        float vv = red[ph][lane & 31];
        vv += __shfl_xor(vv, 4);
        vv += __shfl_xor(vv, 8);
        vv += __shfl_xor(vv, 16);
        const float t0 = read_lane(vv, 0);
        const float t1 = read_lane(vv, 1);
        const float t2 = read_lane(vv, 2);
        const float t3 = read_lane(vv, 3);

        const float a0 = pre0 * rsqrtf(t0 * (1.0f / CH) + EPS);
        const float a1 = pre1 * rsqrtf(t1 * (1.0f / CH) + EPS);
        const float a2 = pre2 * rsqrtf(t2 * (1.0f / CH) + EPS);
        const float a3 = pre3 * rsqrtf(t3 * (1.0f / CH) + EPS);

        f32x4 wu;
        wu.x = wv.x * (a0 * x0.x + a1 * x1.x + a2 * x2.x + a3 * x3.x);
        wu.y = wv.y * (a0 * x0.y + a1 * x1.y + a2 * x2.y + a3 * x3.y);
        wu.z = wv.z * (a0 * x0.z + a1 * x1.z + a2 * x2.z + a3 * x3.z);
        wu.w = wv.w * (a0 * x0.w + a1 * x1.w + a2 * x2.w + a3 * x3.w);

        f32x4* yp = (f32x4*)y + (size_t)b * (NB * CH / 4) + t;
        f32x4 o;
        o.x = H00 * x0.x + H01 * x1.x + H02 * x2.x + H03 * x3.x + ps0 * wu.x;
        o.y = H00 * x0.y + H01 * x1.y + H02 * x2.y + H03 * x3.y + ps0 * wu.y;
        o.z = H00 * x0.z + H01 * x1.z + H02 * x2.z + H03 * x3.z + ps0 * wu.z;
        o.w = H00 * x0.w + H01 * x1.w + H02 * x2.w + H03 * x3.w + ps0 * wu.w;
        __builtin_nontemporal_store(o, yp);
        o.x = H10 * x0.x + H11 * x1.x + H12 * x2.x + H13 * x3.x + ps1 * wu.x;
        o.y = H10 * x0.y + H11 * x1.y + H12 * x2.y + H13 * x3.y + ps1 * wu.y;
        o.z = H10 * x0.z + H11 * x1.z + H12 * x2.z + H13 * x3.z + ps1 * wu.z;
        o.w = H10 * x0.w + H11 * x1.w + H12 * x2.w + H13 * x3.w + ps1 * wu.w;
        __builtin_nontemporal_store(o, yp + (CH / 4));
        o.x = H20 * x0.x + H21 * x1.x + H22 * x2.x + H23 * x3.x + ps2 * wu.x;
        o.y = H20 * x0.y + H21 * x1.y + H22 * x2.y + H23 * x3.y + ps2 * wu.y;
        o.z = H20 * x0.z + H21 * x1.z + H22 * x2.z + H23 * x3.z + ps2 * wu.z;
        o.w = H20 * x0.w + H21 * x1.w + H22 * x2.w + H23 * x3.w + ps2 * wu.w;
        __builtin_nontemporal_store(o, yp + 2 * (CH / 4));
        o.x = H30 * x0.x + H31 * x1.x + H32 * x2.x + H33 * x3.x + ps3 * wu.x;
        o.y = H30 * x0.y + H31 * x1.y + H32 * x2.y + H33 * x3.y + ps3 * wu.y;
        o.z = H30 * x0.z + H31 * x1.z + H32 * x2.z + H33 * x3.z + ps3 * wu.z;
        o.w = H30 * x0.w + H31 * x1.w + H32 * x2.w + H33 * x3.w + ps3 * wu.w;
        __builtin_nontemporal_store(o, yp + 3 * (CH / 4));
    };

    // Depth-2 pipeline over 8 tokens: processing k issues loads for k+2.
    process(b0 + 0, xA0, xA1, xA2, xA3, 0, true,  b0 + 2, xC0, xC1, xC2, xC3);
    process(b0 + 1, xB0, xB1, xB2, xB3, 1, true,  b0 + 3, xA0, xA1, xA2, xA3);
    process(b0 + 2, xC0, xC1, xC2, xC3, 0, true,  b0 + 4, xB0, xB1, xB2, xB3);
    process(b0 + 3, xA0, xA1, xA2, xA3, 1, true,  b0 + 5, xC0, xC1, xC2, xC3);
    process(b0 + 4, xB0, xB1, xB2, xB3, 0, true,  b0 + 6, xA0, xA1, xA2, xA3);
    process(b0 + 5, xC0, xC1, xC2, xC3, 1, true,  b0 + 7, xB0, xB1, xB2, xB3);
    process(b0 + 6, xA0, xA1, xA2, xA3, 0, false, 0,      xC0, xC1, xC2, xC3);
    process(b0 + 7, xB0, xB1, xB2, xB3, 1, false, 0,      xC0, xC1, xC2, xC3);
}

extern "C" void kernel_launch(void* const* d_in, const int* in_sizes, int n_in,
                              void* d_out, int out_size, void* d_ws, size_t ws_size,
                              hipStream_t stream) {
    const float* x      = (const float*)d_in[0];   // [B, N, C]
    const float* wgt    = (const float*)d_in[1];   // [C]
    const float* h_pre  = (const float*)d_in[2];   // [N]
    const float* h_post = (const float*)d_in[3];   // [N]
    const float* h_res  = (const float*)d_in[4];   // [N, N]
    float* y = (float*)d_out;                      // [B, N, C]

    mhc_fused<<<NBLK, TPB, 0, stream>>>(x, wgt, h_pre, h_post, h_res, y);
}

// Round 11
// 99.337 us; speedup vs baseline: 1.2537x; 1.0197x over previous
//
#include <hip/hip_runtime.h>
#include <math.h>

#define B_TOK 8192
#define NB 4
#define CH 2048
#define TPB 512            // 8 waves/block
#define TOK_PER_BLK 2      // fine-grained blocks: 128 KB traffic each
#define NBLK (B_TOK / TOK_PER_BLK)   // 4096 blocks
#define SINK_ITERS 20
#define EPS 1e-5f

typedef float f32x4 __attribute__((ext_vector_type(4)));

__device__ __forceinline__ float bcast_first(float v) {
    return __uint_as_float(__builtin_amdgcn_readfirstlane(__float_as_uint(v)));
}
__device__ __forceinline__ float read_lane(float v, int l) {
    return __uint_as_float(__builtin_amdgcn_readlane(__float_as_uint(v), l));
}

// R8 structure, TOK_PER_BLK 8 -> 2 (NBLK 1024 -> 4096): granularity/tail
// probe. Per-block prologue (sinkhorn, w) overlaps the two tokens' loads,
// which are both issued upfront. Single-lever A/B vs R8 (102.0us).
__global__ __launch_bounds__(TPB) void mhc_fused(
    const float* __restrict__ x,
    const float* __restrict__ w,
    const float* __restrict__ H_pre,
    const float* __restrict__ H_post,
    const float* __restrict__ H_res,
    float* __restrict__ y)
{
    const int t = threadIdx.x;
    const int wave = t >> 6;
    const int lane = t & 63;
    const int b0 = blockIdx.x * TOK_PER_BLK;

    __shared__ float red[2][32];   // [phase][wave*4 + branch]

    // ---- Issue BOTH tokens' loads before anything else ----
    f32x4 xA0, xA1, xA2, xA3, xB0, xB1, xB2, xB3;
    {
        const f32x4* p = (const f32x4*)x + (size_t)(b0 + 0) * (NB * CH / 4) + t;
        xA0 = __builtin_nontemporal_load(p);
        xA1 = __builtin_nontemporal_load(p + (CH / 4));
        xA2 = __builtin_nontemporal_load(p + 2 * (CH / 4));
        xA3 = __builtin_nontemporal_load(p + 3 * (CH / 4));
        const f32x4* q = (const f32x4*)x + (size_t)(b0 + 1) * (NB * CH / 4) + t;
        xB0 = __builtin_nontemporal_load(q);
        xB1 = __builtin_nontemporal_load(q + (CH / 4));
        xB2 = __builtin_nontemporal_load(q + 2 * (CH / 4));
        xB3 = __builtin_nontemporal_load(q + 3 * (CH / 4));
    }
    const f32x4 wv = ((const f32x4*)w)[t];

    // ---- Lane-parallel Sinkhorn (runs while the loads above are in flight) --
    const int e = lane & 15;
    float v = expf(H_res[e]);
    #pragma unroll 1
    for (int it = 0; it < SINK_ITERS; ++it) {
        float s = v + __shfl_xor(v, 1);
        s += __shfl_xor(s, 2);
        v *= __builtin_amdgcn_rcpf(s + EPS);
        s = v + __shfl_xor(v, 4);
        s += __shfl_xor(s, 8);
        v *= __builtin_amdgcn_rcpf(s + EPS);
    }
    const float H00 = read_lane(v, 0),  H01 = read_lane(v, 1),
                H02 = read_lane(v, 2),  H03 = read_lane(v, 3);
    const float H10 = read_lane(v, 4),  H11 = read_lane(v, 5),
                H12 = read_lane(v, 6),  H13 = read_lane(v, 7);
    const float H20 = read_lane(v, 8),  H21 = read_lane(v, 9),
                H22 = read_lane(v, 10), H23 = read_lane(v, 11);
    const float H30 = read_lane(v, 12), H31 = read_lane(v, 13),
                H32 = read_lane(v, 14), H33 = read_lane(v, 15);

    const float pre0 = bcast_first(1.0f / (1.0f + expf(-H_pre[0])));
    const float pre1 = bcast_first(1.0f / (1.0f + expf(-H_pre[1])));
    const float pre2 = bcast_first(1.0f / (1.0f + expf(-H_pre[2])));
    const float pre3 = bcast_first(1.0f / (1.0f + expf(-H_pre[3])));
    const float ps0  = bcast_first(1.0f / (1.0f + expf(-H_post[0])));
    const float ps1  = bcast_first(1.0f / (1.0f + expf(-H_post[1])));
    const float ps2  = bcast_first(1.0f / (1.0f + expf(-H_post[2])));
    const float ps3  = bcast_first(1.0f / (1.0f + expf(-H_post[3])));

    auto process = [&](int b, f32x4 x0, f32x4 x1, f32x4 x2, f32x4 x3, int ph) {
        float s0 = x0.x * x0.x + x0.y * x0.y + x0.z * x0.z + x0.w * x0.w;
        float s1 = x1.x * x1.x + x1.y * x1.y + x1.z * x1.z + x1.w * x1.w;
        float s2 = x2.x * x2.x + x2.y * x2.y + x2.z * x2.z + x2.w * x2.w;
        float s3 = x3.x * x3.x + x3.y * x3.y + x3.z * x3.z + x3.w * x3.w;

        // Fold 4 values -> 1 per lane (3 shuffles), then 4-step butterfly.
        float a01 = (lane & 1) ? s1 : s0;
        float b01 = (lane & 1) ? s0 : s1;
        a01 += __shfl_xor(b01, 1);
        float a23 = (lane & 1) ? s3 : s2;
        float b23 = (lane & 1) ? s2 : s3;
        a23 += __shfl_xor(b23, 1);
        float c = (lane & 2) ? a23 : a01;
        float d = (lane & 2) ? a01 : a23;
        c += __shfl_xor(d, 2);
        c += __shfl_xor(c, 4);
        c += __shfl_xor(c, 8);
        c += __shfl_xor(c, 16);
        c += __shfl_xor(c, 32);
        if (lane < 4) red[ph][wave * 4 + lane] = c;

        // LDS-only barrier: do NOT drain vmcnt (loads stay in flight)
        __builtin_amdgcn_sched_barrier(0);
        asm volatile("s_waitcnt lgkmcnt(0)" ::: "memory");
        __builtin_amdgcn_s_barrier();
        __builtin_amdgcn_sched_barrier(0);

        // Cross-wave combine: conflict-free read, 3 shuffles, 4 readlane.
        float vv = red[ph][lane & 31];
        vv += __shfl_xor(vv, 4);
        vv += __shfl_xor(vv, 8);
        vv += __shfl_xor(vv, 16);
        const float t0 = read_lane(vv, 0);
        const float t1 = read_lane(vv, 1);
        const float t2 = read_lane(vv, 2);
        const float t3 = read_lane(vv, 3);

        const float a0 = pre0 * rsqrtf(t0 * (1.0f / CH) + EPS);
        const float a1 = pre1 * rsqrtf(t1 * (1.0f / CH) + EPS);
        const float a2 = pre2 * rsqrtf(t2 * (1.0f / CH) + EPS);
        const float a3 = pre3 * rsqrtf(t3 * (1.0f / CH) + EPS);

        f32x4 wu;
        wu.x = wv.x * (a0 * x0.x + a1 * x1.x + a2 * x2.x + a3 * x3.x);
        wu.y = wv.y * (a0 * x0.y + a1 * x1.y + a2 * x2.y + a3 * x3.y);
        wu.z = wv.z * (a0 * x0.z + a1 * x1.z + a2 * x2.z + a3 * x3.z);
        wu.w = wv.w * (a0 * x0.w + a1 * x1.w + a2 * x2.w + a3 * x3.w);

        f32x4* yp = (f32x4*)y + (size_t)b * (NB * CH / 4) + t;
        f32x4 o;
        o.x = H00 * x0.x + H01 * x1.x + H02 * x2.x + H03 * x3.x + ps0 * wu.x;
        o.y = H00 * x0.y + H01 * x1.y + H02 * x2.y + H03 * x3.y + ps0 * wu.y;
        o.z = H00 * x0.z + H01 * x1.z + H02 * x2.z + H03 * x3.z + ps0 * wu.z;
        o.w = H00 * x0.w + H01 * x1.w + H02 * x2.w + H03 * x3.w + ps0 * wu.w;
        __builtin_nontemporal_store(o, yp);
        o.x = H10 * x0.x + H11 * x1.x + H12 * x2.x + H13 * x3.x + ps1 * wu.x;
        o.y = H10 * x0.y + H11 * x1.y + H12 * x2.y + H13 * x3.y + ps1 * wu.y;
        o.z = H10 * x0.z + H11 * x1.z + H12 * x2.z + H13 * x3.z + ps1 * wu.z;
        o.w = H10 * x0.w + H11 * x1.w + H12 * x2.w + H13 * x3.w + ps1 * wu.w;
        __builtin_nontemporal_store(o, yp + (CH / 4));
        o.x = H20 * x0.x + H21 * x1.x + H22 * x2.x + H23 * x3.x + ps2 * wu.x;
        o.y = H20 * x0.y + H21 * x1.y + H22 * x2.y + H23 * x3.y + ps2 * wu.y;
        o.z = H20 * x0.z + H21 * x1.z + H22 * x2.z + H23 * x3.z + ps2 * wu.z;
        o.w = H20 * x0.w + H21 * x1.w + H22 * x2.w + H23 * x3.w + ps2 * wu.w;
        __builtin_nontemporal_store(o, yp + 2 * (CH / 4));
        o.x = H30 * x0.x + H31 * x1.x + H32 * x2.x + H33 * x3.x + ps3 * wu.x;
        o.y = H30 * x0.y + H31 * x1.y + H32 * x2.y + H33 * x3.y + ps3 * wu.y;
        o.z = H30 * x0.z + H31 * x1.z + H32 * x2.z + H33 * x3.z + ps3 * wu.z;
        o.w = H30 * x0.w + H31 * x1.w + H32 * x2.w + H33 * x3.w + ps3 * wu.w;
        __builtin_nontemporal_store(o, yp + 3 * (CH / 4));
    };

    process(b0 + 0, xA0, xA1, xA2, xA3, 0);
    process(b0 + 1, xB0, xB1, xB2, xB3, 1);
}

extern "C" void kernel_launch(void* const* d_in, const int* in_sizes, int n_in,
                              void* d_out, int out_size, void* d_ws, size_t ws_size,
                              hipStream_t stream) {
    const float* x      = (const float*)d_in[0];   // [B, N, C]
    const float* wgt    = (const float*)d_in[1];   // [C]
    const float* h_pre  = (const float*)d_in[2];   // [N]
    const float* h_post = (const float*)d_in[3];   // [N]
    const float* h_res  = (const float*)d_in[4];   // [N, N]
    float* y = (float*)d_out;                      // [B, N, C]

    mhc_fused<<<NBLK, TPB, 0, stream>>>(x, wgt, h_pre, h_post, h_res, y);
}

// Round 12
// 95.617 us; speedup vs baseline: 1.3024x; 1.0389x over previous
//
#include <hip/hip_runtime.h>
#include <math.h>

#define B_TOK 8192
#define NB 4
#define CH 2048
#define TPB 512            // 8 waves/block
#define NBLK B_TOK         // one token per block: finest granularity
#define SINK_ITERS 20
#define EPS 1e-5f

typedef float f32x4 __attribute__((ext_vector_type(4)));

__device__ __forceinline__ float bcast_first(float v) {
    return __uint_as_float(__builtin_amdgcn_readfirstlane(__float_as_uint(v)));
}
__device__ __forceinline__ float read_lane(float v, int l) {
    return __uint_as_float(__builtin_amdgcn_readlane(__float_as_uint(v), l));
}

// R11 structure at TOK_PER_BLK=1 (8192 blocks, 64KB each): granularity
// endpoint probe. Loads issue first, lane-parallel sinkhorn overlaps them,
// single barrier, store, retire. Single-lever A/B vs R11 (99.3us).
__global__ __launch_bounds__(TPB) void mhc_fused(
    const float* __restrict__ x,
    const float* __restrict__ w,
    const float* __restrict__ H_pre,
    const float* __restrict__ H_post,
    const float* __restrict__ H_res,
    float* __restrict__ y)
{
    const int t = threadIdx.x;
    const int wave = t >> 6;
    const int lane = t & 63;
    const int b = blockIdx.x;

    __shared__ float red[32];   // [wave*4 + branch]

    // ---- Issue the token's loads before anything else ----
    f32x4 x0, x1, x2, x3;
    {
        const f32x4* p = (const f32x4*)x + (size_t)b * (NB * CH / 4) + t;
        x0 = __builtin_nontemporal_load(p);
        x1 = __builtin_nontemporal_load(p + (CH / 4));
        x2 = __builtin_nontemporal_load(p + 2 * (CH / 4));
        x3 = __builtin_nontemporal_load(p + 3 * (CH / 4));
    }
    const f32x4 wv = ((const f32x4*)w)[t];

    // ---- Lane-parallel Sinkhorn (runs while the loads above are in flight) --
    const int e = lane & 15;
    float v = expf(H_res[e]);
    #pragma unroll 1
    for (int it = 0; it < SINK_ITERS; ++it) {
        float s = v + __shfl_xor(v, 1);
        s += __shfl_xor(s, 2);
        v *= __builtin_amdgcn_rcpf(s + EPS);
        s = v + __shfl_xor(v, 4);
        s += __shfl_xor(s, 8);
        v *= __builtin_amdgcn_rcpf(s + EPS);
    }
    const float H00 = read_lane(v, 0),  H01 = read_lane(v, 1),
                H02 = read_lane(v, 2),  H03 = read_lane(v, 3);
    const float H10 = read_lane(v, 4),  H11 = read_lane(v, 5),
                H12 = read_lane(v, 6),  H13 = read_lane(v, 7);
    const float H20 = read_lane(v, 8),  H21 = read_lane(v, 9),
                H22 = read_lane(v, 10), H23 = read_lane(v, 11);
    const float H30 = read_lane(v, 12), H31 = read_lane(v, 13),
                H32 = read_lane(v, 14), H33 = read_lane(v, 15);

    const float pre0 = bcast_first(1.0f / (1.0f + expf(-H_pre[0])));
    const float pre1 = bcast_first(1.0f / (1.0f + expf(-H_pre[1])));
    const float pre2 = bcast_first(1.0f / (1.0f + expf(-H_pre[2])));
    const float pre3 = bcast_first(1.0f / (1.0f + expf(-H_pre[3])));
    const float ps0  = bcast_first(1.0f / (1.0f + expf(-H_post[0])));
    const float ps1  = bcast_first(1.0f / (1.0f + expf(-H_post[1])));
    const float ps2  = bcast_first(1.0f / (1.0f + expf(-H_post[2])));
    const float ps3  = bcast_first(1.0f / (1.0f + expf(-H_post[3])));

    // ---- Per-branch sum of squares ----
    float s0 = x0.x * x0.x + x0.y * x0.y + x0.z * x0.z + x0.w * x0.w;
    float s1 = x1.x * x1.x + x1.y * x1.y + x1.z * x1.z + x1.w * x1.w;
    float s2 = x2.x * x2.x + x2.y * x2.y + x2.z * x2.z + x2.w * x2.w;
    float s3 = x3.x * x3.x + x3.y * x3.y + x3.z * x3.z + x3.w * x3.w;

    // Fold 4 values -> 1 per lane (3 shuffles), then 4-step butterfly.
    float a01 = (lane & 1) ? s1 : s0;
    float b01 = (lane & 1) ? s0 : s1;
    a01 += __shfl_xor(b01, 1);
    float a23 = (lane & 1) ? s3 : s2;
    float b23 = (lane & 1) ? s2 : s3;
    a23 += __shfl_xor(b23, 1);
    float c = (lane & 2) ? a23 : a01;
    float d = (lane & 2) ? a01 : a23;
    c += __shfl_xor(d, 2);
    c += __shfl_xor(c, 4);
    c += __shfl_xor(c, 8);
    c += __shfl_xor(c, 16);
    c += __shfl_xor(c, 32);
    if (lane < 4) red[wave * 4 + lane] = c;

    // LDS-only barrier: no vmcnt drain (no loads need to be complete here
    // beyond what ss already consumed).
    __builtin_amdgcn_sched_barrier(0);
    asm volatile("s_waitcnt lgkmcnt(0)" ::: "memory");
    __builtin_amdgcn_s_barrier();
    __builtin_amdgcn_sched_barrier(0);

    // Cross-wave combine: conflict-free read, 3 shuffles, 4 readlane.
    float vv = red[lane & 31];
    vv += __shfl_xor(vv, 4);
    vv += __shfl_xor(vv, 8);
    vv += __shfl_xor(vv, 16);
    const float t0 = read_lane(vv, 0);
    const float t1 = read_lane(vv, 1);
    const float t2 = read_lane(vv, 2);
    const float t3 = read_lane(vv, 3);

    const float a0 = pre0 * rsqrtf(t0 * (1.0f / CH) + EPS);
    const float a1 = pre1 * rsqrtf(t1 * (1.0f / CH) + EPS);
    const float a2 = pre2 * rsqrtf(t2 * (1.0f / CH) + EPS);
    const float a3 = pre3 * rsqrtf(t3 * (1.0f / CH) + EPS);

    f32x4 wu;
    wu.x = wv.x * (a0 * x0.x + a1 * x1.x + a2 * x2.x + a3 * x3.x);
    wu.y = wv.y * (a0 * x0.y + a1 * x1.y + a2 * x2.y + a3 * x3.y);
    wu.z = wv.z * (a0 * x0.z + a1 * x1.z + a2 * x2.z + a3 * x3.z);
    wu.w = wv.w * (a0 * x0.w + a1 * x1.w + a2 * x2.w + a3 * x3.w);

    f32x4* yp = (f32x4*)y + (size_t)b * (NB * CH / 4) + t;
    f32x4 o;
    o.x = H00 * x0.x + H01 * x1.x + H02 * x2.x + H03 * x3.x + ps0 * wu.x;
    o.y = H00 * x0.y + H01 * x1.y + H02 * x2.y + H03 * x3.y + ps0 * wu.y;
    o.z = H00 * x0.z + H01 * x1.z + H02 * x2.z + H03 * x3.z + ps0 * wu.z;
    o.w = H00 * x0.w + H01 * x1.w + H02 * x2.w + H03 * x3.w + ps0 * wu.w;
    __builtin_nontemporal_store(o, yp);
    o.x = H10 * x0.x + H11 * x1.x + H12 * x2.x + H13 * x3.x + ps1 * wu.x;
    o.y = H10 * x0.y + H11 * x1.y + H12 * x2.y + H13 * x3.y + ps1 * wu.y;
    o.z = H10 * x0.z + H11 * x1.z + H12 * x2.z + H13 * x3.z + ps1 * wu.z;
    o.w = H10 * x0.w + H11 * x1.w + H12 * x2.w + H13 * x3.w + ps1 * wu.w;
    __builtin_nontemporal_store(o, yp + (CH / 4));
    o.x = H20 * x0.x + H21 * x1.x + H22 * x2.x + H23 * x3.x + ps2 * wu.x;
    o.y = H20 * x0.y + H21 * x1.y + H22 * x2.y + H23 * x3.y + ps2 * wu.y;
    o.z = H20 * x0.z + H21 * x1.z + H22 * x2.z + H23 * x3.z + ps2 * wu.z;
    o.w = H20 * x0.w + H21 * x1.w + H22 * x2.w + H23 * x3.w + ps2 * wu.w;
    __builtin_nontemporal_store(o, yp + 2 * (CH / 4));
    o.x = H30 * x0.x + H31 * x1.x + H32 * x2.x + H33 * x3.x + ps3 * wu.x;
    o.y = H30 * x0.y + H31 * x1.y + H32 * x2.y + H33 * x3.y + ps3 * wu.y;
    o.z = H30 * x0.z + H31 * x1.z + H32 * x2.z + H33 * x3.z + ps3 * wu.z;
    o.w = H30 * x0.w + H31 * x1.w + H32 * x2.w + H33 * x3.w + ps3 * wu.w;
    __builtin_nontemporal_store(o, yp + 3 * (CH / 4));
}

extern "C" void kernel_launch(void* const* d_in, const int* in_sizes, int n_in,
                              void* d_out, int out_size, void* d_ws, size_t ws_size,
                              hipStream_t stream) {
    const float* x      = (const float*)d_in[0];   // [B, N, C]
    const float* wgt    = (const float*)d_in[1];   // [C]
    const float* h_pre  = (const float*)d_in[2];   // [N]
    const float* h_post = (const float*)d_in[3];   // [N]
    const float* h_res  = (const float*)d_in[4];   // [N, N]
    float* y = (float*)d_out;                      // [B, N, C]

    mhc_fused<<<NBLK, TPB, 0, stream>>>(x, wgt, h_pre, h_post, h_res, y);
}

// Round 13
// 93.883 us; speedup vs baseline: 1.3265x; 1.0185x over previous
//
#include <hip/hip_runtime.h>
#include <math.h>

#define B_TOK 8192
#define NB 4
#define CH 2048
#define TPB 512            // 8 waves/block
#define NBLK B_TOK         // one token per block
#define SINK_ITERS 20
#define EPS 1e-5f

typedef float f32x4 __attribute__((ext_vector_type(4)));

__device__ __forceinline__ float bcast_first(float v) {
    return __uint_as_float(__builtin_amdgcn_readfirstlane(__float_as_uint(v)));
}
__device__ __forceinline__ float read_lane(float v, int l) {
    return __uint_as_float(__builtin_amdgcn_readlane(__float_as_uint(v), l));
}

// Kernel 1: one-wave lane-parallel Sinkhorn + sigmoids -> 24 floats in ws.
// ws[0..15] = H row-major, ws[16..19] = pre, ws[20..23] = post.
__global__ void mhc_sinkhorn(const float* __restrict__ H_pre,
                             const float* __restrict__ H_post,
                             const float* __restrict__ H_res,
                             float* __restrict__ ws)
{
    const int lane = threadIdx.x & 63;
    const int e = lane & 15;
    float v = expf(H_res[e]);
    #pragma unroll 1
    for (int it = 0; it < SINK_ITERS; ++it) {
        float s = v + __shfl_xor(v, 1);
        s += __shfl_xor(s, 2);
        v *= __builtin_amdgcn_rcpf(s + EPS);
        s = v + __shfl_xor(v, 4);
        s += __shfl_xor(s, 8);
        v *= __builtin_amdgcn_rcpf(s + EPS);
    }
    if (lane < 16) ws[e] = v;
    if (lane < 4)  ws[16 + lane] = 1.0f / (1.0f + expf(-H_pre[lane]));
    if (lane >= 4 && lane < 8) {
        int n = lane - 4;
        ws[20 + n] = 1.0f / (1.0f + expf(-H_post[n]));
    }
}

// Kernel 2: R12 structure minus the per-block sinkhorn chain. Mixing
// scalars come from ws at constant offsets (scalar loads, hidden under the
// x loads). Block critical path: loads -> reduce -> stores. Single-lever
// A/B vs R12 (95.6us).
__global__ __launch_bounds__(TPB) void mhc_main(const float* __restrict__ x,
                                                const float* __restrict__ w,
                                                const float* __restrict__ ws,
                                                float* __restrict__ y)
{
    const int t = threadIdx.x;
    const int wave = t >> 6;
    const int lane = t & 63;
    const int b = blockIdx.x;

    __shared__ float red[32];   // [wave*4 + branch]

    // ---- Issue the token's loads before anything else ----
    f32x4 x0, x1, x2, x3;
    {
        const f32x4* p = (const f32x4*)x + (size_t)b * (NB * CH / 4) + t;
        x0 = __builtin_nontemporal_load(p);
        x1 = __builtin_nontemporal_load(p + (CH / 4));
        x2 = __builtin_nontemporal_load(p + 2 * (CH / 4));
        x3 = __builtin_nontemporal_load(p + 3 * (CH / 4));
    }
    const f32x4 wv = ((const f32x4*)w)[t];

    // Uniform mixing scalars: constant offsets from a uniform pointer ->
    // s_load into SGPRs; latency hidden under the x loads above.
    const float H00 = ws[0],  H01 = ws[1],  H02 = ws[2],  H03 = ws[3];
    const float H10 = ws[4],  H11 = ws[5],  H12 = ws[6],  H13 = ws[7];
    const float H20 = ws[8],  H21 = ws[9],  H22 = ws[10], H23 = ws[11];
    const float H30 = ws[12], H31 = ws[13], H32 = ws[14], H33 = ws[15];
    const float pre0 = ws[16], pre1 = ws[17], pre2 = ws[18], pre3 = ws[19];
    const float ps0  = ws[20], ps1  = ws[21], ps2  = ws[22], ps3  = ws[23];

    // ---- Per-branch sum of squares ----
    float s0 = x0.x * x0.x + x0.y * x0.y + x0.z * x0.z + x0.w * x0.w;
    float s1 = x1.x * x1.x + x1.y * x1.y + x1.z * x1.z + x1.w * x1.w;
    float s2 = x2.x * x2.x + x2.y * x2.y + x2.z * x2.z + x2.w * x2.w;
    float s3 = x3.x * x3.x + x3.y * x3.y + x3.z * x3.z + x3.w * x3.w;

    // Fold 4 values -> 1 per lane (3 shuffles), then 4-step butterfly.
    float a01 = (lane & 1) ? s1 : s0;
    float b01 = (lane & 1) ? s0 : s1;
    a01 += __shfl_xor(b01, 1);
    float a23 = (lane & 1) ? s3 : s2;
    float b23 = (lane & 1) ? s2 : s3;
    a23 += __shfl_xor(b23, 1);
    float c = (lane & 2) ? a23 : a01;
    float d = (lane & 2) ? a01 : a23;
    c += __shfl_xor(d, 2);
    c += __shfl_xor(c, 4);
    c += __shfl_xor(c, 8);
    c += __shfl_xor(c, 16);
    c += __shfl_xor(c, 32);
    if (lane < 4) red[wave * 4 + lane] = c;

    // LDS-only barrier: no vmcnt drain.
    __builtin_amdgcn_sched_barrier(0);
    asm volatile("s_waitcnt lgkmcnt(0)" ::: "memory");
    __builtin_amdgcn_s_barrier();
    __builtin_amdgcn_sched_barrier(0);

    // Cross-wave combine: conflict-free read, 3 shuffles, 4 readlane.
    float vv = red[lane & 31];
    vv += __shfl_xor(vv, 4);
    vv += __shfl_xor(vv, 8);
    vv += __shfl_xor(vv, 16);
    const float t0 = read_lane(vv, 0);
    const float t1 = read_lane(vv, 1);
    const float t2 = read_lane(vv, 2);
    const float t3 = read_lane(vv, 3);

    const float a0 = pre0 * rsqrtf(t0 * (1.0f / CH) + EPS);
    const float a1 = pre1 * rsqrtf(t1 * (1.0f / CH) + EPS);
    const float a2 = pre2 * rsqrtf(t2 * (1.0f / CH) + EPS);
    const float a3 = pre3 * rsqrtf(t3 * (1.0f / CH) + EPS);

    f32x4 wu;
    wu.x = wv.x * (a0 * x0.x + a1 * x1.x + a2 * x2.x + a3 * x3.x);
    wu.y = wv.y * (a0 * x0.y + a1 * x1.y + a2 * x2.y + a3 * x3.y);
    wu.z = wv.z * (a0 * x0.z + a1 * x1.z + a2 * x2.z + a3 * x3.z);
    wu.w = wv.w * (a0 * x0.w + a1 * x1.w + a2 * x2.w + a3 * x3.w);

    f32x4* yp = (f32x4*)y + (size_t)b * (NB * CH / 4) + t;
    f32x4 o;
    o.x = H00 * x0.x + H01 * x1.x + H02 * x2.x + H03 * x3.x + ps0 * wu.x;
    o.y = H00 * x0.y + H01 * x1.y + H02 * x2.y + H03 * x3.y + ps0 * wu.y;
    o.z = H00 * x0.z + H01 * x1.z + H02 * x2.z + H03 * x3.z + ps0 * wu.z;
    o.w = H00 * x0.w + H01 * x1.w + H02 * x2.w + H03 * x3.w + ps0 * wu.w;
    __builtin_nontemporal_store(o, yp);
    o.x = H10 * x0.x + H11 * x1.x + H12 * x2.x + H13 * x3.x + ps1 * wu.x;
    o.y = H10 * x0.y + H11 * x1.y + H12 * x2.y + H13 * x3.y + ps1 * wu.y;
    o.z = H10 * x0.z + H11 * x1.z + H12 * x2.z + H13 * x3.z + ps1 * wu.z;
    o.w = H10 * x0.w + H11 * x1.w + H12 * x2.w + H13 * x3.w + ps1 * wu.w;
    __builtin_nontemporal_store(o, yp + (CH / 4));
    o.x = H20 * x0.x + H21 * x1.x + H22 * x2.x + H23 * x3.x + ps2 * wu.x;
    o.y = H20 * x0.y + H21 * x1.y + H22 * x2.y + H23 * x3.y + ps2 * wu.y;
    o.z = H20 * x0.z + H21 * x1.z + H22 * x2.z + H23 * x3.z + ps2 * wu.z;
    o.w = H20 * x0.w + H21 * x1.w + H22 * x2.w + H23 * x3.w + ps2 * wu.w;
    __builtin_nontemporal_store(o, yp + 2 * (CH / 4));
    o.x = H30 * x0.x + H31 * x1.x + H32 * x2.x + H33 * x3.x + ps3 * wu.x;
    o.y = H30 * x0.y + H31 * x1.y + H32 * x2.y + H33 * x3.y + ps3 * wu.y;
    o.z = H30 * x0.z + H31 * x1.z + H32 * x2.z + H33 * x3.z + ps3 * wu.z;
    o.w = H30 * x0.w + H31 * x1.w + H32 * x2.w + H33 * x3.w + ps3 * wu.w;
    __builtin_nontemporal_store(o, yp + 3 * (CH / 4));
}

extern "C" void kernel_launch(void* const* d_in, const int* in_sizes, int n_in,
                              void* d_out, int out_size, void* d_ws, size_t ws_size,
                              hipStream_t stream) {
    const float* x      = (const float*)d_in[0];   // [B, N, C]
    const float* wgt    = (const float*)d_in[1];   // [C]
    const float* h_pre  = (const float*)d_in[2];   // [N]
    const float* h_post = (const float*)d_in[3];   // [N]
    const float* h_res  = (const float*)d_in[4];   // [N, N]
    float* y  = (float*)d_out;                     // [B, N, C]
    float* ws = (float*)d_ws;                      // >= 24 floats

    mhc_sinkhorn<<<1, 64, 0, stream>>>(h_pre, h_post, h_res, ws);
    mhc_main<<<NBLK, TPB, 0, stream>>>(x, wgt, ws, y);
}